// Round 5
// baseline (192.567 us; speedup 1.0000x reference)
//
#include <hip/hip_runtime.h>
#include <hip/hip_bf16.h>

// Problem constants (T,S,W,D,C,K) = (16,16,10,512,64,512)
#define W_  10
#define D_  512
#define SW_ 160      // S*W
#define N1_ 1024     // 2*D
#define KT_ 512      // triplets per (t,w)

typedef __bf16 bf16x8 __attribute__((ext_vector_type(8)));
typedef float  f32x4  __attribute__((ext_vector_type(4)));

// async global->LDS, 16B per lane (global addr per-lane; LDS dest = wave base + lane*16)
__device__ __forceinline__ void async16(const void* g, void* l) {
  __builtin_amdgcn_global_load_lds(
      (__attribute__((address_space(1))) void*)(g),
      (__attribute__((address_space(3))) void*)(l), 16, 0, 0);
}

__device__ __forceinline__ float lo16(unsigned v) { return __uint_as_float(v << 16); }
__device__ __forceinline__ float hi16(unsigned v) { return __uint_as_float(v & 0xffff0000u); }
__device__ __forceinline__ unsigned short f2bu(float x) {
  __hip_bfloat16 b = __float2bfloat16(x);
  return *(unsigned short*)&b;
}
__device__ __forceinline__ float bu2f(unsigned short u) {
  return __uint_as_float(((unsigned)u) << 16);
}

// device-scope spin barrier for co-resident grids (ctr pre-zeroed by prep kernel)
__device__ __forceinline__ void gridbar(int* ctr, int target) {
  __syncthreads();
  if (threadIdx.x == 0) {
    __threadfence();
    __hip_atomic_fetch_add(ctr, 1, __ATOMIC_ACQ_REL, __HIP_MEMORY_SCOPE_AGENT);
    while (__hip_atomic_load(ctr, __ATOMIC_ACQUIRE, __HIP_MEMORY_SCOPE_AGENT) < target)
      __builtin_amdgcn_s_sleep(2);
    __threadfence();
  }
  __syncthreads();
}

// ================= K0: prep — cast x, transpose W1, hi/lo-transpose tail weights, zero flags
// grid: [0,256) cast | [256,1792) W1 tiles | [1792,3360) tail-weight tiles
__global__ __launch_bounds__(256) void prep(
    const float* __restrict__ xin, const float* __restrict__ W1,
    const float* __restrict__ W2, const float* __restrict__ W3,
    const float* __restrict__ W4, const float* __restrict__ Wc,
    unsigned short* __restrict__ xbf, unsigned short* __restrict__ w1t,
    unsigned short* __restrict__ W2h, unsigned short* __restrict__ W2l,
    unsigned short* __restrict__ W3h, unsigned short* __restrict__ W3l,
    unsigned short* __restrict__ W4h, unsigned short* __restrict__ W4l,
    unsigned short* __restrict__ Wch, unsigned short* __restrict__ Wcl,
    int* __restrict__ flags)
{
  __shared__ float tile[32 * 33];
  const int bx = blockIdx.x, tid = threadIdx.x;
  if (bx == 0 && tid < 16) flags[tid] = 0;

  if (bx < 256) {  // cast 1310720 floats -> bf16, 5 float4 per thread
    int base = bx * 256 + tid;
#pragma unroll
    for (int rep = 0; rep < 5; ++rep) {
      int e = (rep * 65536 + base) * 4;
      float4 v = *(const float4*)(xin + e);
      ushort4 o = { f2bu(v.x), f2bu(v.y), f2bu(v.z), f2bu(v.w) };
      *(ushort4*)(xbf + e) = o;
    }
    return;
  }

  const int c = tid & 31, rr = tid >> 5;
  if (bx < 1792) {  // W1 [1536][1024] f32 -> w1t [1024][1536] bf16
    int q = bx - 256;
    int n0 = (q & 31) << 5, k0 = (q >> 5) << 5;
#pragma unroll
    for (int i = 0; i < 4; ++i) {
      int r = rr + i * 8;
      tile[r * 33 + c] = W1[(size_t)(k0 + r) * N1_ + n0 + c];
    }
    __syncthreads();
#pragma unroll
    for (int i = 0; i < 4; ++i) {
      int r = rr + i * 8;
      w1t[(size_t)(n0 + r) * 1536 + k0 + c] = f2bu(tile[c * 33 + r]);
    }
    return;
  }

  // tail weights: [R][C] f32 -> [C][R] bf16 hi + lo
  int q = bx - 1792;
  const float* src; unsigned short *dh, *dl; int R, C, rt, ct;
  if (q < 512)       { src = W2; dh = W2h; dl = W2l; R = 1024; C = 512;  rt = q >> 4;          ct = q & 15; }
  else if (q < 1024) { src = W3; dh = W3h; dl = W3l; R = 512;  C = 1024; rt = (q - 512) >> 5;  ct = (q - 512) & 31; }
  else if (q < 1536) { src = W4; dh = W4h; dl = W4l; R = 1024; C = 512;  rt = (q - 1024) >> 4; ct = (q - 1024) & 15; }
  else               { src = Wc; dh = Wch; dl = Wcl; R = 512;  C = 64;   rt = (q - 1536) >> 1; ct = (q - 1536) & 1; }
  int r0 = rt << 5, c0 = ct << 5;
#pragma unroll
  for (int i = 0; i < 4; ++i) {
    int r = rr + i * 8;
    tile[r * 33 + c] = src[(size_t)(r0 + r) * C + c0 + c];
  }
  __syncthreads();
#pragma unroll
  for (int i = 0; i < 4; ++i) {
    int r = rr + i * 8;
    float v = tile[c * 33 + r];
    unsigned short h = f2bu(v);
    size_t off = (size_t)(c0 + r) * R + r0 + c;
    dh[off] = h;
    dl[off] = f2bu(v - bu2f(h));
  }
}

// ================= K1: fused P-tile GEMM + gather/relu/reduce -> Hs (bf16 hi/lo)
__global__ __launch_bounds__(256) void group_kernel(
    const unsigned short* __restrict__ xbf,   // [16][160][512]
    const unsigned short* __restrict__ w1t,   // [1024][1536]
    const int* __restrict__ tidx,             // [16][10][3][512]
    const float* __restrict__ b1,             // [1024]
    unsigned short* __restrict__ Hsh,         // [160][1024]
    unsigned short* __restrict__ Hsl)
{
  __shared__ __align__(16) char smem[47872];
  char* Abuf  = smem;                       // [0,20480) phase 1
  char* Bbuf  = smem + 20480;               // [20480,32768) phase 1
  char* Ptile = smem;                       // [0,34560) phase 2 (overlaps staging)
  int*  idx_s = (int*)(smem + 34560);       // [2][1536] ints = 12288 B
  float* red  = (float*)(smem + 46848);     // [2][128] floats = 1024 B

  const int tid = threadIdx.x;
  const int bx  = blockIdx.x;
  const int t   = bx >> 5;
  const int n0  = (bx & 31) << 5;           // 32-col output window

  const int ln = tid & 63, wv = tid >> 6;
  const int wr = wv >> 1, wc = wv & 1;      // 2x2 wave grid: 80 rows x 48 cols each
  const int col16 = ln & 15, quad = ln >> 4;

  const unsigned short* xt = xbf + (size_t)t * (SW_ * D_);

  int aoff[5], lofA[5];
#pragma unroll
  for (int s = 0; s < 5; ++s) {             // A: 160 rows x 8 chunks = 1280
    int i = s * 256 + tid, r = i >> 3, q = i & 7;
    aoff[s] = r * 512 + ((q ^ (r & 7)) << 3);
    lofA[s] = i << 4;
  }
  int boff[3], lofB[3];
#pragma unroll
  for (int s = 0; s < 3; ++s) {             // B: 96 rows x 8 chunks = 768
    int i = s * 256 + tid, r = i >> 3, q = i & 7;
    int nc = r & 31, j = r >> 5;
    boff[s] = (n0 + nc) * 1536 + j * 512 + ((q ^ (r & 7)) << 3);
    lofB[s] = i << 4;
  }

  f32x4 acc[5][3];
#pragma unroll
  for (int a = 0; a < 5; ++a)
#pragma unroll
    for (int b = 0; b < 3; ++b)
      acc[a][b] = (f32x4){0.f, 0.f, 0.f, 0.f};

  // ---- phase 1: K-loop
#pragma unroll 1
  for (int kk = 0; kk < 512; kk += 64) {
    __syncthreads();
#pragma unroll
    for (int s = 0; s < 5; ++s) async16(xt + aoff[s] + kk, Abuf + lofA[s]);
#pragma unroll
    for (int s = 0; s < 3; ++s) async16(w1t + boff[s] + kk, Bbuf + lofB[s]);
    __syncthreads();

#pragma unroll
    for (int ks = 0; ks < 2; ++ks) {
      const int qq = (ks << 2) + quad;
      bf16x8 af[5], bfr[3];
#pragma unroll
      for (int a = 0; a < 5; ++a) {
        int rm = wr * 80 + a * 16 + col16;
        af[a] = *(const bf16x8*)(Abuf + rm * 128 + ((qq ^ (rm & 7)) << 4));
      }
#pragma unroll
      for (int b = 0; b < 3; ++b) {
        int rn = wc * 48 + b * 16 + col16;
        bfr[b] = *(const bf16x8*)(Bbuf + rn * 128 + ((qq ^ (rn & 7)) << 4));
      }
#pragma unroll
      for (int a = 0; a < 5; ++a)
#pragma unroll
        for (int b = 0; b < 3; ++b)
          acc[a][b] = __builtin_amdgcn_mfma_f32_16x16x32_bf16(af[a], bfr[b], acc[a][b], 0, 0, 0);
    }
  }

  __syncthreads();   // staging reads done; smem becomes Ptile

  // ---- write P to LDS as bf16, layout [j][sw][nc], row stride 72 B
#pragma unroll
  for (int a = 0; a < 5; ++a)
#pragma unroll
    for (int b = 0; b < 3; ++b) {
      int cidx = wc * 48 + b * 16 + col16;     // 0..95
      int j = cidx >> 5, nc = cidx & 31;
      int mb = wr * 80 + a * 16 + quad * 4;
#pragma unroll
      for (int r = 0; r < 4; ++r)
        *(unsigned short*)(Ptile + (j * 160 + mb + r) * 72 + nc * 2) =
            f2bu(acc[a][b][r]);
    }

  // ---- phase 2: gather + relu + reduce per w (double-buffered idx, deferred Hs write)
  const int nq = tid & 7;                    // 4 cols: nc = nq*4..+3
  const int kq = tid >> 3;                   // 0..31
  const float4 bias4 = *(const float4*)(b1 + n0 + (nq << 2));
  const int* tbase = tidx + (size_t)t * 10 * 1536;

  // stage idx for w=0 into buf 0 (drained by first loop-top barrier)
  {
    const int* src = tbase;
    char* dst = (char*)idx_s;
    async16(src + (tid << 2), dst + (tid << 4));
    if (tid < 128) async16(src + 1024 + (tid << 2), dst + 4096 + (tid << 4));
  }

#pragma unroll 1
  for (int w = 0; w < 10; ++w) {
    __syncthreads();   // Ptile visible; idx[w] staged; prev red buffer complete
    if (w < 9) {       // stage idx[w+1] into the other buffer
      const int* src = tbase + (w + 1) * 1536;
      char* dst = (char*)idx_s + ((w + 1) & 1) * 6144;
      async16(src + (tid << 2), dst + (tid << 4));
      if (tid < 128) async16(src + 1024 + (tid << 2), dst + 4096 + (tid << 4));
    }
    if (w > 0 && tid < 32) {   // deferred Hs write for w-1
      const float* rb = red + ((w - 1) & 1) * 128;
      float s = rb[tid] + rb[32 + tid] + rb[64 + tid] + rb[96 + tid];
      unsigned short h = f2bu(s);
      size_t off = (size_t)(t * 10 + (w - 1)) * N1_ + n0 + tid;
      Hsh[off] = h; Hsl[off] = f2bu(s - bu2f(h));
    }

    const int* ib = idx_s + (w & 1) * 1536;
    f32x4 a4 = (f32x4){0.f, 0.f, 0.f, 0.f};
#pragma unroll
    for (int u = 0; u < 4; ++u) {
      const int kb = (kq << 4) + (u << 2);
      int4 i0 = *(const int4*)(ib + kb);
      int4 i1 = *(const int4*)(ib + 512 + kb);
      int4 i2 = *(const int4*)(ib + 1024 + kb);
#define STEP(IA, IB, IC)                                                          \
      {                                                                           \
        uint2 p0 = *(const uint2*)(Ptile + (IA) * 72 + (nq << 3));                \
        uint2 p1 = *(const uint2*)(Ptile + 11520 + (IB) * 72 + (nq << 3));        \
        uint2 p2 = *(const uint2*)(Ptile + 23040 + (IC) * 72 + (nq << 3));        \
        a4.x += fmaxf(lo16(p0.x) + lo16(p1.x) + lo16(p2.x) + bias4.x, 0.f);       \
        a4.y += fmaxf(hi16(p0.x) + hi16(p1.x) + hi16(p2.x) + bias4.y, 0.f);       \
        a4.z += fmaxf(lo16(p0.y) + lo16(p1.y) + lo16(p2.y) + bias4.z, 0.f);       \
        a4.w += fmaxf(hi16(p0.y) + hi16(p1.y) + hi16(p2.y) + bias4.w, 0.f);       \
      }
      STEP(i0.x, i1.x, i2.x)
      STEP(i0.y, i1.y, i2.y)
      STEP(i0.z, i1.z, i2.z)
      STEP(i0.w, i1.w, i2.w)
#undef STEP
    }

#pragma unroll
    for (int off = 8; off <= 32; off <<= 1) {
      a4.x += __shfl_xor(a4.x, off);
      a4.y += __shfl_xor(a4.y, off);
      a4.z += __shfl_xor(a4.z, off);
      a4.w += __shfl_xor(a4.w, off);
    }
    if ((ln >> 3) == 0)
      *(f32x4*)(red + (w & 1) * 128 + wv * 32 + (nq << 2)) = a4;
  }
  __syncthreads();
  if (tid < 32) {   // final w=9
    const float* rb = red + 128;            // (9&1)=1
    float s = rb[tid] + rb[32 + tid] + rb[64 + tid] + rb[96 + tid];
    unsigned short h = f2bu(s);
    size_t off = (size_t)(t * 10 + 9) * N1_ + n0 + tid;
    Hsh[off] = h; Hsl[off] = f2bu(s - bu2f(h));
  }
}

// ---------------- tail helper: 80x64 output tile, A/B in bf16 hi/lo pairs, BK=64
__device__ __forceinline__ void gemm80(
    char* AH, char* AL, char* BH, char* BL,
    const unsigned short* __restrict__ Ah, const unsigned short* __restrict__ Al, int m0,
    const unsigned short* __restrict__ Bh, const unsigned short* __restrict__ Bl, int n0,
    int K, f32x4 acc[5], int tid)
{
  const int ln = tid & 63, wv = tid >> 6, col16 = ln & 15, quad = ln >> 4;
#pragma unroll 1
  for (int kk = 0; kk < K; kk += 64) {
    __syncthreads();
#pragma unroll
    for (int p = 0; p < 9; ++p) {
      int i = p * 256 + tid;
      if (i < 640) {
        int r = i >> 3, q = i & 7;
        async16(Ah + (size_t)(m0 + r) * K + kk + ((q ^ (r & 7)) << 3), AH + (i << 4));
      } else if (i < 1280) {
        int j = i - 640, r = j >> 3, q = j & 7;
        async16(Al + (size_t)(m0 + r) * K + kk + ((q ^ (r & 7)) << 3), AL + (j << 4));
      } else if (i < 1792) {
        int j = i - 1280, r = j >> 3, q = j & 7;
        async16(Bh + (size_t)(n0 + r) * K + kk + ((q ^ (r & 7)) << 3), BH + (j << 4));
      } else {
        int j = i - 1792, r = j >> 3, q = j & 7;
        async16(Bl + (size_t)(n0 + r) * K + kk + ((q ^ (r & 7)) << 3), BL + (j << 4));
      }
    }
    __syncthreads();
#pragma unroll
    for (int ks = 0; ks < 2; ++ks) {
      const int qq = (ks << 2) + quad;
      const int rn = (wv << 4) + col16;
      bf16x8 bh = *(const bf16x8*)(BH + rn * 128 + ((qq ^ (rn & 7)) << 4));
      bf16x8 bl = *(const bf16x8*)(BL + rn * 128 + ((qq ^ (rn & 7)) << 4));
#pragma unroll
      for (int a = 0; a < 5; ++a) {
        int rm = (a << 4) + col16;
        bf16x8 ah = *(const bf16x8*)(AH + rm * 128 + ((qq ^ (rm & 7)) << 4));
        bf16x8 al = *(const bf16x8*)(AL + rm * 128 + ((qq ^ (rm & 7)) << 4));
        acc[a] = __builtin_amdgcn_mfma_f32_16x16x32_bf16(ah, bh, acc[a], 0, 0, 0);
        acc[a] = __builtin_amdgcn_mfma_f32_16x16x32_bf16(ah, bl, acc[a], 0, 0, 0);
        acc[a] = __builtin_amdgcn_mfma_f32_16x16x32_bf16(al, bh, acc[a], 0, 0, 0);
      }
    }
  }
}

__device__ __forceinline__ void store_pair(
    f32x4 acc[5], int m0, int n0, const float* __restrict__ bias, float scale,
    bool relu, unsigned short* __restrict__ Oh, unsigned short* __restrict__ Ol,
    int ldo, int tid)
{
  const int ln = tid & 63, wv = tid >> 6, col16 = ln & 15, quad = ln >> 4;
  const int col = n0 + (wv << 4) + col16;
  const float bb = bias[col] * scale;
#pragma unroll
  for (int a = 0; a < 5; ++a)
#pragma unroll
    for (int r = 0; r < 4; ++r) {
      int row = m0 + (a << 4) + (quad << 2) + r;
      float v = acc[a][r] + bb;
      if (relu) v = fmaxf(v, 0.f);
      unsigned short h = f2bu(v);
      size_t off = (size_t)row * ldo + col;
      Oh[off] = h; Ol[off] = f2bu(v - bu2f(h));
    }
}

// ================= K2: fused tail, 32 co-resident blocks, 3 grid barriers.
__global__ __launch_bounds__(256) void tail_kernel(
    const unsigned short* __restrict__ Hsh, const unsigned short* __restrict__ Hsl,
    const unsigned short* __restrict__ W2h, const unsigned short* __restrict__ W2l,
    const unsigned short* __restrict__ W3h, const unsigned short* __restrict__ W3l,
    const unsigned short* __restrict__ W4h, const unsigned short* __restrict__ W4l,
    const unsigned short* __restrict__ Wch, const unsigned short* __restrict__ Wcl,
    const float* __restrict__ b2, const float* __restrict__ b3,
    const float* __restrict__ b4, const float* __restrict__ bc,
    unsigned short* __restrict__ gh, unsigned short* __restrict__ gl,
    unsigned short* __restrict__ uh, unsigned short* __restrict__ ul,
    unsigned short* __restrict__ oh, unsigned short* __restrict__ ol,
    int* __restrict__ ctrs, float* __restrict__ out)
{
  __shared__ __align__(16) char sm[36864];
  char* AH = sm, *AL = sm + 10240, *BH = sm + 20480, *BL = sm + 28672;
  const int bx = blockIdx.x, tid = threadIdx.x;
  f32x4 acc[5];

  // stage 1: g = Hs@W2 + 512*b2   (16 active blocks)
  if (bx < 16) {
#pragma unroll
    for (int a = 0; a < 5; ++a) acc[a] = (f32x4){0.f, 0.f, 0.f, 0.f};
    int m0 = (bx & 1) * 80, n0 = (bx >> 1) << 6;
    gemm80(AH, AL, BH, BL, Hsh, Hsl, m0, W2h, W2l, n0, 1024, acc, tid);
    store_pair(acc, m0, n0, b2, (float)KT_, false, gh, gl, 512, tid);
  }
  gridbar(&ctrs[0], 32);

  // stage 2: u = relu(g@W3 + b3)  (all 32 blocks)
  {
#pragma unroll
    for (int a = 0; a < 5; ++a) acc[a] = (f32x4){0.f, 0.f, 0.f, 0.f};
    int m0 = (bx & 1) * 80, n0 = (bx >> 1) << 6;
    gemm80(AH, AL, BH, BL, gh, gl, m0, W3h, W3l, n0, 512, acc, tid);
    store_pair(acc, m0, n0, b3, 1.f, true, uh, ul, 1024, tid);
  }
  gridbar(&ctrs[1], 32);

  // stage 3: o = u@W4 + b4        (16 active blocks)
  if (bx < 16) {
#pragma unroll
    for (int a = 0; a < 5; ++a) acc[a] = (f32x4){0.f, 0.f, 0.f, 0.f};
    int m0 = (bx & 1) * 80, n0 = (bx >> 1) << 6;
    gemm80(AH, AL, BH, BL, uh, ul, m0, W4h, W4l, n0, 1024, acc, tid);
    store_pair(acc, m0, n0, b4, 1.f, false, oh, ol, 512, tid);
  }
  gridbar(&ctrs[2], 32);

  // stage 4: score = o@Wc + bc, softmax over 64   (2 active blocks)
  if (bx < 2) {
#pragma unroll
    for (int a = 0; a < 5; ++a) acc[a] = (f32x4){0.f, 0.f, 0.f, 0.f};
    int m0 = bx * 80;
    gemm80(AH, AL, BH, BL, oh, ol, m0, Wch, Wcl, 0, 512, acc, tid);
    __syncthreads();   // done reading LDS frags; reuse as score buffer
    float* sc = (float*)sm;            // [80][64] = 20480 B
    float* rs = (float*)(sm + 20480);  // [80]
    const int ln = tid & 63, wv = tid >> 6, col16 = ln & 15, quad = ln >> 4;
    const int col = (wv << 4) + col16;
    const float bb = bc[col];
#pragma unroll
    for (int a = 0; a < 5; ++a)
#pragma unroll
      for (int r = 0; r < 4; ++r)
        sc[((a << 4) + (quad << 2) + r) * 64 + col] = acc[a][r] + bb;
    __syncthreads();
    if (tid < 80) {
      float m = -1e30f;
      for (int c = 0; c < 64; ++c) m = fmaxf(m, sc[tid * 64 + c]);
      float s = 0.f;
      for (int c = 0; c < 64; ++c) {
        float e = expf(sc[tid * 64 + c] - m);
        sc[tid * 64 + c] = e;
        s += e;
      }
      rs[tid] = 1.f / s;
    }
    __syncthreads();
#pragma unroll
    for (int p = 0; p < 20; ++p) {
      int f = p * 256 + tid, r = f >> 6, c = f & 63;
      out[(size_t)(m0 + r) * 64 + c] = sc[f] * rs[r];
    }
  }
}

extern "C" void kernel_launch(void* const* d_in, const int* in_sizes, int n_in,
                              void* d_out, int out_size, void* d_ws, size_t ws_size,
                              hipStream_t stream) {
  const float* x_in = (const float*)d_in[0];
  const int*   tidx = (const int*)d_in[1];
  const float* W1 = (const float*)d_in[2];
  const float* b1 = (const float*)d_in[3];
  const float* W2 = (const float*)d_in[4];
  const float* b2 = (const float*)d_in[5];
  const float* W3 = (const float*)d_in[6];
  const float* b3 = (const float*)d_in[7];
  const float* W4 = (const float*)d_in[8];
  const float* b4 = (const float*)d_in[9];
  const float* Wc = (const float*)d_in[10];
  const float* bc = (const float*)d_in[11];
  float* out = (float*)d_out;
  (void)in_sizes; (void)n_in; (void)out_size; (void)ws_size;

  char* ws = (char*)d_ws;
  unsigned short* xbf = (unsigned short*)(ws + 0);          // 2,621,440
  unsigned short* w1t = (unsigned short*)(ws + 2621440);    // 3,145,728
  unsigned short* W2h = (unsigned short*)(ws + 5767168);    // 1,048,576 each
  unsigned short* W2l = (unsigned short*)(ws + 6815744);
  unsigned short* W3h = (unsigned short*)(ws + 7864320);
  unsigned short* W3l = (unsigned short*)(ws + 8912896);
  unsigned short* W4h = (unsigned short*)(ws + 9961472);
  unsigned short* W4l = (unsigned short*)(ws + 11010048);
  unsigned short* Wch = (unsigned short*)(ws + 12058624);   // 65,536 each
  unsigned short* Wcl = (unsigned short*)(ws + 12124160);
  unsigned short* Hsh = (unsigned short*)(ws + 12189696);   // 327,680 each
  unsigned short* Hsl = (unsigned short*)(ws + 12517376);
  unsigned short* gh  = (unsigned short*)(ws + 12845056);   // 163,840 each
  unsigned short* gl  = (unsigned short*)(ws + 13008896);
  unsigned short* uh  = (unsigned short*)(ws + 13172736);   // 327,680 each
  unsigned short* ul  = (unsigned short*)(ws + 13500416);
  unsigned short* oh  = (unsigned short*)(ws + 13828096);   // 163,840 each
  unsigned short* ol  = (unsigned short*)(ws + 13991936);
  int* ctrs           = (int*)(ws + 14155776);              // 64 B flags

  prep<<<3360, 256, 0, stream>>>(x_in, W1, W2, W3, W4, Wc,
                                 xbf, w1t, W2h, W2l, W3h, W3l, W4h, W4l, Wch, Wcl, ctrs);

  group_kernel<<<512, 256, 0, stream>>>(xbf, w1t, tidx, b1, Hsh, Hsl);

  tail_kernel<<<32, 256, 0, stream>>>(Hsh, Hsl, W2h, W2l, W3h, W3l, W4h, W4l, Wch, Wcl,
                                      b2, b3, b4, bc, gh, gl, uh, ul, oh, ol, ctrs, out);
}

// Round 6
// 185.582 us; speedup vs baseline: 1.0376x; 1.0376x over previous
//
#include <hip/hip_runtime.h>
#include <hip/hip_bf16.h>

// Problem constants (T,S,W,D,C,K) = (16,16,10,512,64,512)
#define W_  10
#define D_  512
#define SW_ 160      // S*W
#define N1_ 1024     // 2*D
#define KT_ 512      // triplets per (t,w)

typedef __bf16 bf16x8 __attribute__((ext_vector_type(8)));
typedef float  f32x4  __attribute__((ext_vector_type(4)));

// async global->LDS, 16B per lane (global addr per-lane; LDS dest = wave base + lane*16)
__device__ __forceinline__ void async16(const void* g, void* l) {
  __builtin_amdgcn_global_load_lds(
      (__attribute__((address_space(1))) void*)(g),
      (__attribute__((address_space(3))) void*)(l), 16, 0, 0);
}

__device__ __forceinline__ float lo16(unsigned v) { return __uint_as_float(v << 16); }
__device__ __forceinline__ float hi16(unsigned v) { return __uint_as_float(v & 0xffff0000u); }
__device__ __forceinline__ unsigned short f2bu(float x) {
  __hip_bfloat16 b = __float2bfloat16(x);
  return *(unsigned short*)&b;
}
__device__ __forceinline__ float bu2f(unsigned short u) {
  return __uint_as_float(((unsigned)u) << 16);
}

// ================= K0: prep — cast x, transpose W1, hi/lo-transpose tail weights
// grid: [0,256) cast | [256,1792) W1 tiles | [1792,3360) tail-weight tiles
__global__ __launch_bounds__(256) void prep(
    const float* __restrict__ xin, const float* __restrict__ W1,
    const float* __restrict__ W2, const float* __restrict__ W3,
    const float* __restrict__ W4, const float* __restrict__ Wc,
    unsigned short* __restrict__ xbf, unsigned short* __restrict__ w1t,
    unsigned short* __restrict__ W2h, unsigned short* __restrict__ W2l,
    unsigned short* __restrict__ W3h, unsigned short* __restrict__ W3l,
    unsigned short* __restrict__ W4h, unsigned short* __restrict__ W4l,
    unsigned short* __restrict__ Wch, unsigned short* __restrict__ Wcl)
{
  __shared__ float tile[32 * 33];
  const int bx = blockIdx.x, tid = threadIdx.x;

  if (bx < 256) {  // cast 1310720 floats -> bf16, 5 float4 per thread
    int base = bx * 256 + tid;
#pragma unroll
    for (int rep = 0; rep < 5; ++rep) {
      int e = (rep * 65536 + base) * 4;
      float4 v = *(const float4*)(xin + e);
      ushort4 o = { f2bu(v.x), f2bu(v.y), f2bu(v.z), f2bu(v.w) };
      *(ushort4*)(xbf + e) = o;
    }
    return;
  }

  const int c = tid & 31, rr = tid >> 5;
  if (bx < 1792) {  // W1 [1536][1024] f32 -> w1t [1024][1536] bf16
    int q = bx - 256;
    int n0 = (q & 31) << 5, k0 = (q >> 5) << 5;
#pragma unroll
    for (int i = 0; i < 4; ++i) {
      int r = rr + i * 8;
      tile[r * 33 + c] = W1[(size_t)(k0 + r) * N1_ + n0 + c];
    }
    __syncthreads();
#pragma unroll
    for (int i = 0; i < 4; ++i) {
      int r = rr + i * 8;
      w1t[(size_t)(n0 + r) * 1536 + k0 + c] = f2bu(tile[c * 33 + r]);
    }
    return;
  }

  // tail weights: [R][C] f32 -> [C][R] bf16 hi + lo
  int q = bx - 1792;
  const float* src; unsigned short *dh, *dl; int R, C, rt, ct;
  if (q < 512)       { src = W2; dh = W2h; dl = W2l; R = 1024; C = 512;  rt = q >> 4;          ct = q & 15; }
  else if (q < 1024) { src = W3; dh = W3h; dl = W3l; R = 512;  C = 1024; rt = (q - 512) >> 5;  ct = (q - 512) & 31; }
  else if (q < 1536) { src = W4; dh = W4h; dl = W4l; R = 1024; C = 512;  rt = (q - 1024) >> 4; ct = (q - 1024) & 15; }
  else               { src = Wc; dh = Wch; dl = Wcl; R = 512;  C = 64;   rt = (q - 1536) >> 1; ct = (q - 1536) & 1; }
  int r0 = rt << 5, c0 = ct << 5;
#pragma unroll
  for (int i = 0; i < 4; ++i) {
    int r = rr + i * 8;
    tile[r * 33 + c] = src[(size_t)(r0 + r) * C + c0 + c];
  }
  __syncthreads();
#pragma unroll
  for (int i = 0; i < 4; ++i) {
    int r = rr + i * 8;
    float v = tile[c * 33 + r];
    unsigned short h = f2bu(v);
    size_t off = (size_t)(c0 + r) * R + r0 + c;
    dh[off] = h;
    dl[off] = f2bu(v - bu2f(h));
  }
}

// ================= K1: fused P-tile GEMM + gather/relu/reduce -> Hs (bf16 hi/lo)
__global__ __launch_bounds__(256) void group_kernel(
    const unsigned short* __restrict__ xbf,   // [16][160][512]
    const unsigned short* __restrict__ w1t,   // [1024][1536]
    const int* __restrict__ tidx,             // [16][10][3][512]
    const float* __restrict__ b1,             // [1024]
    unsigned short* __restrict__ Hsh,         // [160][1024]
    unsigned short* __restrict__ Hsl)
{
  __shared__ __align__(16) char smem[47872];
  char* Abuf  = smem;                       // [0,20480) phase 1
  char* Bbuf  = smem + 20480;               // [20480,32768) phase 1
  char* Ptile = smem;                       // [0,34560) phase 2 (overlaps staging)
  int*  idx_s = (int*)(smem + 34560);       // [2][1536] ints = 12288 B
  float* red  = (float*)(smem + 46848);     // [2][128] floats = 1024 B

  const int tid = threadIdx.x;
  const int bx  = blockIdx.x;
  const int t   = bx >> 5;
  const int n0  = (bx & 31) << 5;           // 32-col output window

  const int ln = tid & 63, wv = tid >> 6;
  const int wr = wv >> 1, wc = wv & 1;      // 2x2 wave grid: 80 rows x 48 cols each
  const int col16 = ln & 15, quad = ln >> 4;

  const unsigned short* xt = xbf + (size_t)t * (SW_ * D_);

  int aoff[5], lofA[5];
#pragma unroll
  for (int s = 0; s < 5; ++s) {             // A: 160 rows x 8 chunks = 1280
    int i = s * 256 + tid, r = i >> 3, q = i & 7;
    aoff[s] = r * 512 + ((q ^ (r & 7)) << 3);
    lofA[s] = i << 4;
  }
  int boff[3], lofB[3];
#pragma unroll
  for (int s = 0; s < 3; ++s) {             // B: 96 rows x 8 chunks = 768
    int i = s * 256 + tid, r = i >> 3, q = i & 7;
    int nc = r & 31, j = r >> 5;
    boff[s] = (n0 + nc) * 1536 + j * 512 + ((q ^ (r & 7)) << 3);
    lofB[s] = i << 4;
  }

  f32x4 acc[5][3];
#pragma unroll
  for (int a = 0; a < 5; ++a)
#pragma unroll
    for (int b = 0; b < 3; ++b)
      acc[a][b] = (f32x4){0.f, 0.f, 0.f, 0.f};

  // ---- phase 1: K-loop
#pragma unroll 1
  for (int kk = 0; kk < 512; kk += 64) {
    __syncthreads();
#pragma unroll
    for (int s = 0; s < 5; ++s) async16(xt + aoff[s] + kk, Abuf + lofA[s]);
#pragma unroll
    for (int s = 0; s < 3; ++s) async16(w1t + boff[s] + kk, Bbuf + lofB[s]);
    __syncthreads();

#pragma unroll
    for (int ks = 0; ks < 2; ++ks) {
      const int qq = (ks << 2) + quad;
      bf16x8 af[5], bfr[3];
#pragma unroll
      for (int a = 0; a < 5; ++a) {
        int rm = wr * 80 + a * 16 + col16;
        af[a] = *(const bf16x8*)(Abuf + rm * 128 + ((qq ^ (rm & 7)) << 4));
      }
#pragma unroll
      for (int b = 0; b < 3; ++b) {
        int rn = wc * 48 + b * 16 + col16;
        bfr[b] = *(const bf16x8*)(Bbuf + rn * 128 + ((qq ^ (rn & 7)) << 4));
      }
#pragma unroll
      for (int a = 0; a < 5; ++a)
#pragma unroll
        for (int b = 0; b < 3; ++b)
          acc[a][b] = __builtin_amdgcn_mfma_f32_16x16x32_bf16(af[a], bfr[b], acc[a][b], 0, 0, 0);
    }
  }

  __syncthreads();   // staging reads done; smem becomes Ptile

  // ---- write P to LDS as bf16, layout [j][sw][nc], row stride 72 B
#pragma unroll
  for (int a = 0; a < 5; ++a)
#pragma unroll
    for (int b = 0; b < 3; ++b) {
      int cidx = wc * 48 + b * 16 + col16;     // 0..95
      int j = cidx >> 5, nc = cidx & 31;
      int mb = wr * 80 + a * 16 + quad * 4;
#pragma unroll
      for (int r = 0; r < 4; ++r)
        *(unsigned short*)(Ptile + (j * 160 + mb + r) * 72 + nc * 2) =
            f2bu(acc[a][b][r]);
    }

  // ---- phase 2: gather + relu + reduce per w (double-buffered idx, deferred Hs write)
  const int nq = tid & 7;                    // 4 cols: nc = nq*4..+3
  const int kq = tid >> 3;                   // 0..31
  const float4 bias4 = *(const float4*)(b1 + n0 + (nq << 2));
  const int* tbase = tidx + (size_t)t * 10 * 1536;

  {
    const int* src = tbase;
    char* dst = (char*)idx_s;
    async16(src + (tid << 2), dst + (tid << 4));
    if (tid < 128) async16(src + 1024 + (tid << 2), dst + 4096 + (tid << 4));
  }

#pragma unroll 1
  for (int w = 0; w < 10; ++w) {
    __syncthreads();   // Ptile visible; idx[w] staged; prev red buffer complete
    if (w < 9) {       // stage idx[w+1] into the other buffer
      const int* src = tbase + (w + 1) * 1536;
      char* dst = (char*)idx_s + ((w + 1) & 1) * 6144;
      async16(src + (tid << 2), dst + (tid << 4));
      if (tid < 128) async16(src + 1024 + (tid << 2), dst + 4096 + (tid << 4));
    }
    if (w > 0 && tid < 32) {   // deferred Hs write for w-1
      const float* rb = red + ((w - 1) & 1) * 128;
      float s = rb[tid] + rb[32 + tid] + rb[64 + tid] + rb[96 + tid];
      unsigned short h = f2bu(s);
      size_t off = (size_t)(t * 10 + (w - 1)) * N1_ + n0 + tid;
      Hsh[off] = h; Hsl[off] = f2bu(s - bu2f(h));
    }

    const int* ib = idx_s + (w & 1) * 1536;
    f32x4 a4 = (f32x4){0.f, 0.f, 0.f, 0.f};
#pragma unroll
    for (int u = 0; u < 4; ++u) {
      const int kb = (kq << 4) + (u << 2);
      int4 i0 = *(const int4*)(ib + kb);
      int4 i1 = *(const int4*)(ib + 512 + kb);
      int4 i2 = *(const int4*)(ib + 1024 + kb);
#define STEP(IA, IB, IC)                                                          \
      {                                                                           \
        uint2 p0 = *(const uint2*)(Ptile + (IA) * 72 + (nq << 3));                \
        uint2 p1 = *(const uint2*)(Ptile + 11520 + (IB) * 72 + (nq << 3));        \
        uint2 p2 = *(const uint2*)(Ptile + 23040 + (IC) * 72 + (nq << 3));        \
        a4.x += fmaxf(lo16(p0.x) + lo16(p1.x) + lo16(p2.x) + bias4.x, 0.f);       \
        a4.y += fmaxf(hi16(p0.x) + hi16(p1.x) + hi16(p2.x) + bias4.y, 0.f);       \
        a4.z += fmaxf(lo16(p0.y) + lo16(p1.y) + lo16(p2.y) + bias4.z, 0.f);       \
        a4.w += fmaxf(hi16(p0.y) + hi16(p1.y) + hi16(p2.y) + bias4.w, 0.f);       \
      }
      STEP(i0.x, i1.x, i2.x)
      STEP(i0.y, i1.y, i2.y)
      STEP(i0.z, i1.z, i2.z)
      STEP(i0.w, i1.w, i2.w)
#undef STEP
    }

#pragma unroll
    for (int off = 8; off <= 32; off <<= 1) {
      a4.x += __shfl_xor(a4.x, off);
      a4.y += __shfl_xor(a4.y, off);
      a4.z += __shfl_xor(a4.z, off);
      a4.w += __shfl_xor(a4.w, off);
    }
    if ((ln >> 3) == 0)
      *(f32x4*)(red + (w & 1) * 128 + wv * 32 + (nq << 2)) = a4;
  }
  __syncthreads();
  if (tid < 32) {   // final w=9
    const float* rb = red + 128;
    float s = rb[tid] + rb[32 + tid] + rb[64 + tid] + rb[96 + tid];
    unsigned short h = f2bu(s);
    size_t off = (size_t)(t * 10 + 9) * N1_ + n0 + tid;
    Hsh[off] = h; Hsl[off] = f2bu(s - bu2f(h));
  }
}

// ---------------- shared tail tile: 80x64 output, A/B bf16 hi/lo, BK=64, 3-MFMA product
__device__ __forceinline__ void gemm80(
    char* AH, char* AL, char* BH, char* BL,
    const unsigned short* __restrict__ Ah, const unsigned short* __restrict__ Al, int m0,
    const unsigned short* __restrict__ Bh, const unsigned short* __restrict__ Bl, int n0,
    int K, f32x4 acc[5], int tid)
{
  const int ln = tid & 63, wv = tid >> 6, col16 = ln & 15, quad = ln >> 4;
#pragma unroll 1
  for (int kk = 0; kk < K; kk += 64) {
    __syncthreads();
#pragma unroll
    for (int p = 0; p < 9; ++p) {
      int i = p * 256 + tid;
      if (i < 640) {
        int r = i >> 3, q = i & 7;
        async16(Ah + (size_t)(m0 + r) * K + kk + ((q ^ (r & 7)) << 3), AH + (i << 4));
      } else if (i < 1280) {
        int j = i - 640, r = j >> 3, q = j & 7;
        async16(Al + (size_t)(m0 + r) * K + kk + ((q ^ (r & 7)) << 3), AL + (j << 4));
      } else if (i < 1792) {
        int j = i - 1280, r = j >> 3, q = j & 7;
        async16(Bh + (size_t)(n0 + r) * K + kk + ((q ^ (r & 7)) << 3), BH + (j << 4));
      } else {
        int j = i - 1792, r = j >> 3, q = j & 7;
        async16(Bl + (size_t)(n0 + r) * K + kk + ((q ^ (r & 7)) << 3), BL + (j << 4));
      }
    }
    __syncthreads();
#pragma unroll
    for (int ks = 0; ks < 2; ++ks) {
      const int qq = (ks << 2) + quad;
      const int rn = (wv << 4) + col16;
      bf16x8 bh = *(const bf16x8*)(BH + rn * 128 + ((qq ^ (rn & 7)) << 4));
      bf16x8 bl = *(const bf16x8*)(BL + rn * 128 + ((qq ^ (rn & 7)) << 4));
#pragma unroll
      for (int a = 0; a < 5; ++a) {
        int rm = (a << 4) + col16;
        bf16x8 ah = *(const bf16x8*)(AH + rm * 128 + ((qq ^ (rm & 7)) << 4));
        bf16x8 al = *(const bf16x8*)(AL + rm * 128 + ((qq ^ (rm & 7)) << 4));
        acc[a] = __builtin_amdgcn_mfma_f32_16x16x32_bf16(ah, bh, acc[a], 0, 0, 0);
        acc[a] = __builtin_amdgcn_mfma_f32_16x16x32_bf16(ah, bl, acc[a], 0, 0, 0);
        acc[a] = __builtin_amdgcn_mfma_f32_16x16x32_bf16(al, bh, acc[a], 0, 0, 0);
      }
    }
  }
}

// ================= K2: standalone tail GEMM stage (separate launches = free coherence)
__global__ __launch_bounds__(256) void tail_gemm(
    const unsigned short* __restrict__ Ah, const unsigned short* __restrict__ Al,
    const unsigned short* __restrict__ Bh, const unsigned short* __restrict__ Bl,
    const float* __restrict__ bias, float bscale, int relu, int K, int N,
    unsigned short* __restrict__ Oh, unsigned short* __restrict__ Ol)
{
  __shared__ __align__(16) char sm[36864];
  char* AH = sm, *AL = sm + 10240, *BH = sm + 20480, *BL = sm + 28672;
  const int tid = threadIdx.x;
  const int m0 = blockIdx.y * 80, n0 = blockIdx.x << 6;
  f32x4 acc[5];
#pragma unroll
  for (int a = 0; a < 5; ++a) acc[a] = (f32x4){0.f, 0.f, 0.f, 0.f};

  gemm80(AH, AL, BH, BL, Ah, Al, m0, Bh, Bl, n0, K, acc, tid);

  const int ln = tid & 63, wv = tid >> 6, col16 = ln & 15, quad = ln >> 4;
  const int col = n0 + (wv << 4) + col16;
  const float bb = bias[col] * bscale;
#pragma unroll
  for (int a = 0; a < 5; ++a)
#pragma unroll
    for (int r = 0; r < 4; ++r) {
      int row = m0 + (a << 4) + (quad << 2) + r;
      float v = acc[a][r] + bb;
      if (relu) v = fmaxf(v, 0.f);
      unsigned short h = f2bu(v);
      size_t off = (size_t)row * N + col;
      Oh[off] = h; Ol[off] = f2bu(v - bu2f(h));
    }
}

// ================= K3: head — score = o@Wc + bc, softmax(64). Grid 2 (80 rows each).
__global__ __launch_bounds__(256) void head_gemm(
    const unsigned short* __restrict__ oh, const unsigned short* __restrict__ ol,
    const unsigned short* __restrict__ Wch, const unsigned short* __restrict__ Wcl,
    const float* __restrict__ bc, float* __restrict__ out)
{
  __shared__ __align__(16) char sm[36864];
  char* AH = sm, *AL = sm + 10240, *BH = sm + 20480, *BL = sm + 28672;
  const int tid = threadIdx.x;
  const int m0 = blockIdx.x * 80;
  f32x4 acc[5];
#pragma unroll
  for (int a = 0; a < 5; ++a) acc[a] = (f32x4){0.f, 0.f, 0.f, 0.f};

  gemm80(AH, AL, BH, BL, oh, ol, m0, Wch, Wcl, 0, 512, acc, tid);

  __syncthreads();   // done with LDS frags; reuse as score buffer
  float* sc = (float*)sm;            // [80][64]
  float* rs = (float*)(sm + 20480);  // [80]
  const int ln = tid & 63, wv = tid >> 6, col16 = ln & 15, quad = ln >> 4;
  const int col = (wv << 4) + col16;
  const float bb = bc[col];
#pragma unroll
  for (int a = 0; a < 5; ++a)
#pragma unroll
    for (int r = 0; r < 4; ++r)
      sc[((a << 4) + (quad << 2) + r) * 64 + col] = acc[a][r] + bb;
  __syncthreads();
  if (tid < 80) {
    float m = -1e30f;
    for (int c = 0; c < 64; ++c) m = fmaxf(m, sc[tid * 64 + c]);
    float s = 0.f;
    for (int c = 0; c < 64; ++c) {
      float e = expf(sc[tid * 64 + c] - m);
      sc[tid * 64 + c] = e;
      s += e;
    }
    rs[tid] = 1.f / s;
  }
  __syncthreads();
#pragma unroll
  for (int p = 0; p < 20; ++p) {
    int f = p * 256 + tid, r = f >> 6, c = f & 63;
    out[(size_t)(m0 + r) * 64 + c] = sc[f] * rs[r];
  }
}

extern "C" void kernel_launch(void* const* d_in, const int* in_sizes, int n_in,
                              void* d_out, int out_size, void* d_ws, size_t ws_size,
                              hipStream_t stream) {
  const float* x_in = (const float*)d_in[0];
  const int*   tidx = (const int*)d_in[1];
  const float* W1 = (const float*)d_in[2];
  const float* b1 = (const float*)d_in[3];
  const float* W2 = (const float*)d_in[4];
  const float* b2 = (const float*)d_in[5];
  const float* W3 = (const float*)d_in[6];
  const float* b3 = (const float*)d_in[7];
  const float* W4 = (const float*)d_in[8];
  const float* b4 = (const float*)d_in[9];
  const float* Wc = (const float*)d_in[10];
  const float* bc = (const float*)d_in[11];
  float* out = (float*)d_out;
  (void)in_sizes; (void)n_in; (void)out_size; (void)ws_size;

  char* ws = (char*)d_ws;
  unsigned short* xbf = (unsigned short*)(ws + 0);          // 2,621,440
  unsigned short* w1t = (unsigned short*)(ws + 2621440);    // 3,145,728
  unsigned short* W2h = (unsigned short*)(ws + 5767168);    // 1,048,576 each
  unsigned short* W2l = (unsigned short*)(ws + 6815744);
  unsigned short* W3h = (unsigned short*)(ws + 7864320);
  unsigned short* W3l = (unsigned short*)(ws + 8912896);
  unsigned short* W4h = (unsigned short*)(ws + 9961472);
  unsigned short* W4l = (unsigned short*)(ws + 11010048);
  unsigned short* Wch = (unsigned short*)(ws + 12058624);   // 65,536 each
  unsigned short* Wcl = (unsigned short*)(ws + 12124160);
  unsigned short* Hsh = (unsigned short*)(ws + 12189696);   // 327,680 each
  unsigned short* Hsl = (unsigned short*)(ws + 12517376);
  unsigned short* gh  = (unsigned short*)(ws + 12845056);   // 163,840 each
  unsigned short* gl  = (unsigned short*)(ws + 13008896);
  unsigned short* uh  = (unsigned short*)(ws + 13172736);   // 327,680 each
  unsigned short* ul  = (unsigned short*)(ws + 13500416);
  unsigned short* oh  = (unsigned short*)(ws + 13828096);   // 163,840 each
  unsigned short* ol  = (unsigned short*)(ws + 13991936);

  prep<<<3360, 256, 0, stream>>>(x_in, W1, W2, W3, W4, Wc,
                                 xbf, w1t, W2h, W2l, W3h, W3l, W4h, W4l, Wch, Wcl);

  group_kernel<<<512, 256, 0, stream>>>(xbf, w1t, tidx, b1, Hsh, Hsl);

  // g = Hs@W2 + 512*b2
  tail_gemm<<<dim3(8, 2), 256, 0, stream>>>(Hsh, Hsl, W2h, W2l, b2, (float)KT_, 0, 1024, 512, gh, gl);
  // u = relu(g@W3 + b3)
  tail_gemm<<<dim3(16, 2), 256, 0, stream>>>(gh, gl, W3h, W3l, b3, 1.f, 1, 512, 1024, uh, ul);
  // o = u@W4 + b4
  tail_gemm<<<dim3(8, 2), 256, 0, stream>>>(uh, ul, W4h, W4l, b4, 1.f, 0, 1024, 512, oh, ol);
  // softmax(o@Wc + bc)
  head_gemm<<<2, 256, 0, stream>>>(oh, ol, Wch, Wcl, bc, out);
}